// Round 6
// baseline (276.882 us; speedup 1.0000x reference)
//
#include <hip/hip_runtime.h>

#define DIM 128
#define CB_ROWS 1024            // rows per coarse bucket (row >> 10)
#define CCAP 18432              // edata0 capacity per coarse bucket (mean 16327, +16 sigma)
#define BK_EDGES 2048           // edges per k_bucket block (782 blocks -> full CU spread)

typedef __attribute__((ext_vector_type(8))) short short8;   // 8 x bf16 (4 VGPR)
typedef __attribute__((ext_vector_type(4))) float f32x4;    // 4 x f32  (4 VGPR)

__device__ __forceinline__ unsigned short f2bf(float f) {   // RNE fp32->bf16
    unsigned u = __float_as_uint(f);
    u += 0x7fffu + ((u >> 16) & 1u);
    return (unsigned short)(u >> 16);
}
__device__ __forceinline__ float bf2f(unsigned short b) {
    return __uint_as_float(((unsigned)b) << 16);
}

// ---- merged pre-pass: input fp32->bf16, W1/W2 fp32->bf16, zero gcur (one launch) ----
__global__ void k_pre(const float4* __restrict__ in, const float* __restrict__ W1,
                      const float* __restrict__ W2, unsigned short* __restrict__ inputb,
                      unsigned short* __restrict__ w1b, unsigned short* __restrict__ w2b,
                      int* __restrict__ gcur, int n4, int nCvt, int nbuk) {
    int b = blockIdx.x;
    if (b < nCvt) {
        int i = b * 256 + threadIdx.x;
        if (i < n4) {
            float4 v = in[i];
            *(ushort4*)(inputb + (long)i * 4) =
                make_ushort4(f2bf(v.x), f2bf(v.y), f2bf(v.z), f2bf(v.w));
        }
    } else if (b < nCvt + 192) {
        int idx = (b - nCvt) * 256 + threadIdx.x;   // 49152 = 16384 + 32768
        if (idx < 16384)      w1b[idx] = f2bf(W1[idx]);
        else                  w2b[idx - 16384] = f2bf(W2[idx - 16384]);
    } else {
        int i = (b - nCvt - 192) * 256 + threadIdx.x;
        if (i < nbuk) gcur[i] = 0;
    }
}

// ---- pass 1: COARSE bucket scatter (98 buckets of 1024 rows) ----
// Runs of ~21 edges per bucket per block (~168B) -> coalesced-ish writes,
// vs the old 782-bucket version's 8B random writes over 19 MB.
// edata0[b*CCAP + pos] = ( (row&1023)<<17 | col , val )    (col < 2^17)
__global__ __launch_bounds__(256) void k_bucket(const int* __restrict__ er,
                                                const int* __restrict__ ec,
                                                const float* __restrict__ ev,
                                                int* __restrict__ gcur,
                                                int2* __restrict__ edata0, int E, int nbuk) {
    __shared__ int lhist[128];
    __shared__ int lpos[128];
    if (threadIdx.x < 128) lhist[threadIdx.x] = 0;
    __syncthreads();
    int e0 = blockIdx.x * BK_EDGES;
    for (int j = 0; j < BK_EDGES; j += 256) {
        int e = e0 + j + threadIdx.x;
        if (e < E) atomicAdd(&lhist[er[e] >> 10], 1);       // int LDS atomic: native
    }
    __syncthreads();
    if (threadIdx.x < nbuk) {
        int c = lhist[threadIdx.x];
        int g = (c > 0) ? atomicAdd(&gcur[threadIdx.x], c) : 0;
        lpos[threadIdx.x] = threadIdx.x * CCAP + g;         // write cursor for this chunk
    }
    __syncthreads();
    for (int j = 0; j < BK_EDGES; j += 256) {
        int e = e0 + j + threadIdx.x;
        if (e < E) {
            int r = er[e], b = r >> 10;
            int p = atomicAdd(&lpos[b], 1);
            if (p < (b + 1) * CCAP)     // capacity guard (statistically never)
                edata0[p] = make_int2(((r & 1023) << 17) | ec[e], __float_as_int(ev[e]));
        }
    }
}

// ---- pass 2: exact global CSR build. One 1024-thread block per coarse bucket. ----
// Scatter writes are confined to this bucket's ~145KB output window (L2-resident,
// dense eviction). Writes absolute rs/re per row; edata becomes dense E-entry CSR.
__global__ __launch_bounds__(1024) void k_csr(const int2* __restrict__ edata0,
                                              const int* __restrict__ gcur,
                                              int2* __restrict__ edata,
                                              int* __restrict__ rs, int* __restrict__ re,
                                              int N, int nbuk) {
    __shared__ int hist[CB_ROWS];
    __shared__ int scan[CB_ROWS];
    __shared__ int lcur[CB_ROWS];
    __shared__ int cbuf[128];
    __shared__ int cbase;
    int b = blockIdx.x, tid = threadIdx.x;
    if (tid < nbuk) { int c = gcur[tid]; cbuf[tid] = (c > CCAP) ? CCAP : c; }
    hist[tid] = 0;
    __syncthreads();
    if (tid == 0) {                     // exclusive scan over 98 bucket counts (LDS, cheap)
        int s = 0;
        for (int i = 0; i < b; ++i) s += cbuf[i];
        cbase = s;
    }
    __syncthreads();
    int base = cbase;
    int cnt = cbuf[b];
    const int2* e0 = edata0 + (long)b * CCAP;
    for (int i = tid; i < cnt; i += 1024) atomicAdd(&hist[e0[i].x >> 17], 1);
    __syncthreads();
    scan[tid] = hist[tid];
    __syncthreads();
    for (int off = 1; off < CB_ROWS; off <<= 1) {           // Hillis-Steele inclusive
        int v = (tid >= off) ? scan[tid - off] : 0;
        __syncthreads();
        scan[tid] += v;
        __syncthreads();
    }
    int excl = scan[tid] - hist[tid];
    lcur[tid] = base + excl;
    int row = b * CB_ROWS + tid;
    if (row < N) { rs[row] = base + excl; re[row] = base + excl + hist[tid]; }
    __syncthreads();
    for (int i = tid; i < cnt; i += 1024) {
        int2 v = e0[i];
        int p = atomicAdd(&lcur[v.x >> 17], 1);
        edata[p] = make_int2(v.x & 0x1FFFF, v.y);           // strip row bits: (col,val)
    }
}

// ---- gather: 16 lanes per row, 4 rows per wave, NO cross-lane reduction tail ----
// Lane (grp, s) owns dims s*8..s*8+7 of its row and accumulates them across ALL
// edges -> after the loop the lane holds the final value (tail = 8 f2bf + 1 store).
// Edges preloaded 16/group (1 coalesced load), broadcast via intra-group shfl;
// 4-unrolled so 4 independent 16B x-loads stay in flight. Register accumulation.
__global__ __launch_bounds__(256) void k_gather(const unsigned short* __restrict__ xb,
                                                const int2* __restrict__ edata,
                                                const int* __restrict__ rs,
                                                const int* __restrict__ re,
                                                unsigned short* __restrict__ aggb, int N) {
    int tid = threadIdx.x, lane = tid & 63, wave = tid >> 6;
    int grp = lane >> 4, s = lane & 15;     // row-group (0..3), dim-slot (0..15)
    int row = blockIdx.x * 16 + wave * 4 + grp;
    int beg = 0, end = 0;
    if (row < N) { beg = rs[row]; end = re[row]; }
    int deg = end - beg;
    int m = deg;                            // wave-uniform max degree over 4 groups
    m = max(m, __shfl_xor(m, 16));
    m = max(m, __shfl_xor(m, 32));
    float pa[8];
#pragma unroll
    for (int k = 0; k < 8; ++k) pa[k] = 0.f;
    const int4* x4 = (const int4*)xb;       // 16 x int4 per 256B x-row
    int bsrc = lane & 48;                   // group base lane for broadcasts

#define ACC8(U, V)                                                         \
    {                                                                      \
        const unsigned* wp_ = (const unsigned*)&(U);                       \
        pa[0] += (V) * __uint_as_float(wp_[0] << 16);                      \
        pa[1] += (V) * __uint_as_float(wp_[0] & 0xffff0000u);              \
        pa[2] += (V) * __uint_as_float(wp_[1] << 16);                      \
        pa[3] += (V) * __uint_as_float(wp_[1] & 0xffff0000u);              \
        pa[4] += (V) * __uint_as_float(wp_[2] << 16);                      \
        pa[5] += (V) * __uint_as_float(wp_[2] & 0xffff0000u);              \
        pa[6] += (V) * __uint_as_float(wp_[3] << 16);                      \
        pa[7] += (V) * __uint_as_float(wp_[3] & 0xffff0000u);              \
    }

    for (int c0 = 0; c0 < m; c0 += 16) {
        int idx = beg + c0 + s;             // lane s holds edge (c0+s) of its group
        int2 ed = (idx < end) ? edata[idx] : make_int2(0, 0);   // pad: col 0, val 0
        int nc = m - c0; if (nc > 16) nc = 16;
        nc = (nc + 3) & ~3;                 // padded slots are (0,0) -> contribute 0
        for (int j = 0; j < nc; j += 4) {
            int cx0 = __shfl(ed.x, bsrc + j);
            int cx1 = __shfl(ed.x, bsrc + j + 1);
            int cx2 = __shfl(ed.x, bsrc + j + 2);
            int cx3 = __shfl(ed.x, bsrc + j + 3);
            float v0 = __int_as_float(__shfl(ed.y, bsrc + j));
            float v1 = __int_as_float(__shfl(ed.y, bsrc + j + 1));
            float v2 = __int_as_float(__shfl(ed.y, bsrc + j + 2));
            float v3 = __int_as_float(__shfl(ed.y, bsrc + j + 3));
            int4 u0 = x4[(long)cx0 * 16 + s];   // 4 independent 16B loads in flight
            int4 u1 = x4[(long)cx1 * 16 + s];
            int4 u2 = x4[(long)cx2 * 16 + s];
            int4 u3 = x4[(long)cx3 * 16 + s];
            ACC8(u0, v0);
            ACC8(u1, v1);
            ACC8(u2, v2);
            ACC8(u3, v3);
        }
    }
#undef ACC8

    if (row < N) {                          // lane stores its 8 final dims (16B)
        short8 o;
#pragma unroll
        for (int k = 0; k < 8; ++k) o[k] = (short)f2bf(pa[k]);
        *(short8*)(aggb + (long)row * DIM + s * 8) = o;
    }
}

// ---- fused MFMA: out = leaky_relu([x+agg@W1^T, x*(agg@W1^T)] @ W2^T) ----
// 64 rows/block, 4 waves; each wave owns 2 output-column tiles for all 64 rows.
// B fragments hoisted into registers once; weight L2 traffic = 1 copy per block.
__global__ __launch_bounds__(256, 4) void k_fused(const unsigned short* __restrict__ aggb,
                                                  const unsigned short* __restrict__ inputb,
                                                  const unsigned short* __restrict__ w1b,
                                                  const unsigned short* __restrict__ w2b,
                                                  float* __restrict__ out, int N) {
    __shared__ __align__(16) unsigned short sh[2 * 64 * 136];   // h0 | h1, rows padded to 136
    int w = threadIdx.x >> 6, lane = threadIdx.x & 63;
    int quad = lane >> 4, lq = lane & 15;
    int blk0 = blockIdx.x * 64;
    unsigned short* sh0 = sh;
    unsigned short* sh1 = sh + 64 * 136;

    // ---- hoisted gemm1 B fragments: nt = 2w, 2w+1 (8 frags = 32 VGPR, issued as a batch)
    short8 b1[2][4];
#pragma unroll
    for (int ntl = 0; ntl < 2; ++ntl)
#pragma unroll
        for (int kb = 0; kb < 4; ++kb)
            b1[ntl][kb] = *(const short8*)(w1b + ((w * 2 + ntl) * 16 + lq) * DIM +
                                           kb * 32 + quad * 8);

    // ---- gemm1 + h write, fused per m-tile to bound VGPR pressure ----
#pragma unroll
    for (int mt = 0; mt < 4; ++mt) {
        short8 afr[4];
        {
            int row = blk0 + mt * 16 + lq; if (row >= N) row = N - 1;
#pragma unroll
            for (int kb = 0; kb < 4; ++kb)
                afr[kb] = *(const short8*)(aggb + (long)row * DIM + kb * 32 + quad * 8);
        }
#pragma unroll
        for (int ntl = 0; ntl < 2; ++ntl) {
            f32x4 c = {0.f, 0.f, 0.f, 0.f};
#pragma unroll
            for (int kb = 0; kb < 4; ++kb)
                c = __builtin_amdgcn_mfma_f32_16x16x32_bf16(afr[kb], b1[ntl][kb], c, 0, 0, 0);
            int nt = w * 2 + ntl;
#pragma unroll
            for (int rg = 0; rg < 4; ++rg) {
                int r = blk0 + mt * 16 + quad * 4 + rg;
                int rr = (r < N) ? r : (N - 1);
                float x = bf2f(inputb[(long)rr * DIM + nt * 16 + lq]);
                float nb = c[rg];
                int off = (mt * 16 + quad * 4 + rg) * 136 + nt * 16 + lq;
                sh0[off] = f2bf(x + nb);
                sh1[off] = f2bf(x * nb);
            }
        }
    }

    // ---- hoisted gemm2 B fragments (16 frags = 64 VGPR), issued BEFORE the barrier ----
    short8 b2[2][8];
#pragma unroll
    for (int ntl = 0; ntl < 2; ++ntl)
#pragma unroll
        for (int kb = 0; kb < 8; ++kb)
            b2[ntl][kb] = *(const short8*)(w2b + ((w * 2 + ntl) * 16 + lq) * 256 +
                                           kb * 32 + quad * 8);
    __syncthreads();

    // ---- gemm2 (K=256 over two h halves) + leaky_relu epilogue, direct store ----
#pragma unroll
    for (int mt = 0; mt < 4; ++mt) {
        int arow = (mt * 16 + lq) * 136;
        short8 a0[4], a1[4];
#pragma unroll
        for (int kb = 0; kb < 4; ++kb) {
            a0[kb] = *(const short8*)(sh0 + arow + kb * 32 + quad * 8);
            a1[kb] = *(const short8*)(sh1 + arow + kb * 32 + quad * 8);
        }
#pragma unroll
        for (int ntl = 0; ntl < 2; ++ntl) {
            f32x4 c = {0.f, 0.f, 0.f, 0.f};
#pragma unroll
            for (int kb = 0; kb < 4; ++kb)
                c = __builtin_amdgcn_mfma_f32_16x16x32_bf16(a0[kb], b2[ntl][kb], c, 0, 0, 0);
#pragma unroll
            for (int kb = 0; kb < 4; ++kb)
                c = __builtin_amdgcn_mfma_f32_16x16x32_bf16(a1[kb], b2[ntl][kb + 4], c, 0, 0, 0);
            int nt = w * 2 + ntl;
#pragma unroll
            for (int rg = 0; rg < 4; ++rg) {
                int r = blk0 + mt * 16 + quad * 4 + rg;
                if (r < N) {
                    float v = c[rg];
                    v = (v > 0.f) ? v : 0.01f * v;
                    out[(long)r * DIM + nt * 16 + lq] = v;
                }
            }
        }
    }
}

extern "C" void kernel_launch(void* const* d_in, const int* in_sizes, int n_in,
                              void* d_out, int out_size, void* d_ws, size_t ws_size,
                              hipStream_t stream) {
    const float* input = (const float*)d_in[0];
    const int*   er    = (const int*)d_in[1];
    const int*   ec    = (const int*)d_in[2];
    const float* ev    = (const float*)d_in[3];
    const float* W1    = (const float*)d_in[4];
    const float* W2    = (const float*)d_in[5];
    int N = in_sizes[0] / DIM;      // 100000
    int E = in_sizes[1];            // 1600000
    float* out = (float*)d_out;
    int nbuk = (N + CB_ROWS - 1) / CB_ROWS;     // 98

    // ---- workspace layout (~65 MB; edata0 overlays aggb: dead by k_gather) ----
    int* ws = (int*)d_ws;
    int* gcur = ws;                                                      // nbuk ints (pad 1024)
    int2* edata = (int2*)(ws + 1024);                                    // E int2 (dense CSR)
    int* rs = (int*)(edata + (long)E);                                   // N ints
    int* re = rs + N;                                                    // N ints
    unsigned short* w1b = (unsigned short*)(re + N);                     // 16384 bf16
    unsigned short* w2b = w1b + 16384;                                   // 32768 bf16
    unsigned short* inputb = w2b + 32768;                                // N*DIM bf16
    unsigned short* aggb = inputb + (long)N * DIM;                       // N*DIM bf16
    int2* edata0 = (int2*)aggb;     // nbuk*CCAP int2 = 14.5 MB <= 25.6 MB aggb region

    int n4 = N * (DIM / 4);
    int nCvt = (n4 + 255) / 256;
    int nZero = (nbuk + 255) / 256;
    k_pre<<<nCvt + 192 + nZero, 256, 0, stream>>>(
        (const float4*)input, W1, W2, inputb, w1b, w2b, gcur, n4, nCvt, nbuk);

    k_bucket<<<(E + BK_EDGES - 1) / BK_EDGES, 256, 0, stream>>>(
        er, ec, ev, gcur, edata0, E, nbuk);

    k_csr<<<nbuk, 1024, 0, stream>>>(edata0, gcur, edata, rs, re, N, nbuk);

    k_gather<<<(N + 15) / 16, 256, 0, stream>>>(inputb, edata, rs, re, aggb, N);

    k_fused<<<(N + 63) / 64, 256, 0, stream>>>(aggb, inputb, w1b, w2b, out, N);
}

// Round 7
// 249.763 us; speedup vs baseline: 1.1086x; 1.1086x over previous
//
#include <hip/hip_runtime.h>

#define DIM 128
#define BROWS 128               // rows per bucket (row >> 7)
#define BCAP 3072               // edata0 capacity per bucket (mean 2046, +22 sigma)
#define NBUK_PAD 800
#define BK_EDGES 6144           // edges per k_bucket block (261 blocks), LDS-staged

typedef __attribute__((ext_vector_type(8))) short short8;   // 8 x bf16 (4 VGPR)
typedef __attribute__((ext_vector_type(4))) float f32x4;    // 4 x f32  (4 VGPR)

__device__ __forceinline__ unsigned short f2bf(float f) {   // RNE fp32->bf16
    unsigned u = __float_as_uint(f);
    u += 0x7fffu + ((u >> 16) & 1u);
    return (unsigned short)(u >> 16);
}
__device__ __forceinline__ float bf2f(unsigned short b) {
    return __uint_as_float(((unsigned)b) << 16);
}

// ---- merged pre-pass: input fp32->bf16, W1/W2 fp32->bf16, zero gcur (one launch) ----
__global__ void k_pre(const float4* __restrict__ in, const float* __restrict__ W1,
                      const float* __restrict__ W2, unsigned short* __restrict__ inputb,
                      unsigned short* __restrict__ w1b, unsigned short* __restrict__ w2b,
                      int* __restrict__ gcur, int n4, int nCvt, int nbuk) {
    int b = blockIdx.x;
    if (b < nCvt) {
        int i = b * 256 + threadIdx.x;
        if (i < n4) {
            float4 v = in[i];
            *(ushort4*)(inputb + (long)i * 4) =
                make_ushort4(f2bf(v.x), f2bf(v.y), f2bf(v.z), f2bf(v.w));
        }
    } else if (b < nCvt + 192) {
        int idx = (b - nCvt) * 256 + threadIdx.x;   // 49152 = 16384 + 32768
        if (idx < 16384)      w1b[idx] = f2bf(W1[idx]);
        else                  w2b[idx - 16384] = f2bf(W2[idx - 16384]);
    } else {
        int i = (b - nCvt - 192) * 256 + threadIdx.x;
        if (i < nbuk) gcur[i] = 0;
    }
}

// ---- pass 1: bucket scatter with LDS PRESORT ----
// Each block sorts 6144 edges into 782 row-buckets inside LDS, then writes each
// bucket's run with CONSECUTIVE LANES -> consecutive addresses (coalesced), vs the
// old per-lane-scattered 8B writes (64 lines per wave-store instruction).
// edata0[bk*BCAP + pos] = ( (row&127)<<17 | col , val )    (col < 2^17)
__global__ __launch_bounds__(1024) void k_bucket(const int* __restrict__ er,
                                                 const int* __restrict__ ec,
                                                 const float* __restrict__ ev,
                                                 int* __restrict__ gcur,
                                                 int2* __restrict__ edata0, int E, int nbuk) {
    __shared__ int2 sed[BK_EDGES];      // 48 KB sorted edge staging
    __shared__ int lhist[NBUK_PAD];
    __shared__ int lscan[NBUK_PAD];
    __shared__ int lpos[NBUK_PAD];
    __shared__ int gbase[NBUK_PAD];
    int tid = threadIdx.x;
    if (tid < NBUK_PAD) lhist[tid] = 0;
    __syncthreads();
    int e0 = blockIdx.x * BK_EDGES;
    int bcnt = E - e0; if (bcnt > BK_EDGES) bcnt = BK_EDGES;
    for (int i = tid; i < bcnt; i += 1024)
        atomicAdd(&lhist[er[e0 + i] >> 7], 1);
    __syncthreads();
    if (tid < NBUK_PAD) lscan[tid] = lhist[tid];
    __syncthreads();
    for (int off = 1; off < NBUK_PAD; off <<= 1) {          // Hillis-Steele inclusive
        int v = (tid < NBUK_PAD && tid >= off) ? lscan[tid - off] : 0;
        __syncthreads();
        if (tid < NBUK_PAD) lscan[tid] += v;
        __syncthreads();
    }
    if (tid < NBUK_PAD) {
        int c = lhist[tid];
        lpos[tid] = lscan[tid] - c;                         // exclusive: LDS write cursor
        gbase[tid] = (c > 0 && tid < nbuk) ? atomicAdd(&gcur[tid], c) : 0;
    }
    __syncthreads();
    for (int i = tid; i < bcnt; i += 1024) {                // LDS scatter (cheap)
        int e = e0 + i;
        int r = er[e], bk = r >> 7;
        int p = atomicAdd(&lpos[bk], 1);
        sed[p] = make_int2(((r & 127) << 17) | ec[e], __float_as_int(ev[e]));
    }
    __syncthreads();
    int wv = tid >> 6, lane = tid & 63;                     // coalesced run write-out
    for (int bk = wv; bk < nbuk; bk += 16) {
        int c = lhist[bk];
        if (c == 0) continue;
        int excl = lscan[bk] - c;
        int gb = gbase[bk];
        long base = (long)bk * BCAP;
        for (int j = lane; j < c; j += 64)
            if (gb + j < BCAP)                              // capacity guard (never)
                edata0[base + gb + j] = sed[excl + j];
    }
}

// ---- gather: one block per 128-row bucket; in-LDS CSR build + register gather ----
// Replaces the old k_csr + k_gather pair: two passes over this bucket's own chunk
// (L2-hot, 16 KB) build a 128-row mini-CSR in LDS; then the proven 16-lane/row
// 4-deep-unrolled register gather reads edge descriptors from LDS (broadcast, free).
__global__ __launch_bounds__(256) void k_gather(const unsigned short* __restrict__ xb,
                                                const int2* __restrict__ edata0,
                                                const int* __restrict__ gcur,
                                                unsigned short* __restrict__ aggb, int N) {
    __shared__ int2 sed[BCAP];          // 24.6 KB row-sorted (col,val)
    __shared__ int hist[BROWS];
    __shared__ int hscan[BROWS];
    __shared__ int lcur[BROWS];
    int tid = threadIdx.x, b = blockIdx.x;
    int cnt = gcur[b]; if (cnt > BCAP) cnt = BCAP;
    const int2* e0 = edata0 + (long)b * BCAP;
    if (tid < BROWS) hist[tid] = 0;
    __syncthreads();
    for (int i = tid; i < cnt; i += 256) atomicAdd(&hist[e0[i].x >> 17], 1);
    __syncthreads();
    if (tid < BROWS) hscan[tid] = hist[tid];
    __syncthreads();
    for (int off = 1; off < BROWS; off <<= 1) {             // Hillis-Steele inclusive
        int v = (tid < BROWS && tid >= off) ? hscan[tid - off] : 0;
        __syncthreads();
        if (tid < BROWS) hscan[tid] += v;
        __syncthreads();
    }
    if (tid < BROWS) lcur[tid] = hscan[tid] - hist[tid];
    __syncthreads();
    for (int i = tid; i < cnt; i += 256) {                  // LDS scatter to row order
        int2 v = e0[i];
        int p = atomicAdd(&lcur[v.x >> 17], 1);
        sed[p] = make_int2(v.x & 0x1FFFF, v.y);
    }
    __syncthreads();

    int slot = tid >> 4, s = tid & 15;      // 16 row-slots, dim-slot s (16B each)
    const int4* x4 = (const int4*)xb;       // 16 x int4 per 256B x-row

#define ACC8(U, V)                                                         \
    {                                                                      \
        const unsigned* wp_ = (const unsigned*)&(U);                       \
        pa[0] += (V) * __uint_as_float(wp_[0] << 16);                      \
        pa[1] += (V) * __uint_as_float(wp_[0] & 0xffff0000u);              \
        pa[2] += (V) * __uint_as_float(wp_[1] << 16);                      \
        pa[3] += (V) * __uint_as_float(wp_[1] & 0xffff0000u);              \
        pa[4] += (V) * __uint_as_float(wp_[2] << 16);                      \
        pa[5] += (V) * __uint_as_float(wp_[2] & 0xffff0000u);              \
        pa[6] += (V) * __uint_as_float(wp_[3] << 16);                      \
        pa[7] += (V) * __uint_as_float(wp_[3] & 0xffff0000u);              \
    }

    for (int k = 0; k < 8; ++k) {           // 8 rows per slot
        int rl = k * 16 + slot;
        int row = b * BROWS + rl;
        int beg = hscan[rl] - hist[rl], end = hscan[rl];
        float pa[8];
#pragma unroll
        for (int t = 0; t < 8; ++t) pa[t] = 0.f;
        int j = beg;
        for (; j + 4 <= end; j += 4) {      // 4 independent 16B x-loads in flight
            int2 q0 = sed[j], q1 = sed[j + 1], q2 = sed[j + 2], q3 = sed[j + 3];
            int4 u0 = x4[(long)q0.x * 16 + s];
            int4 u1 = x4[(long)q1.x * 16 + s];
            int4 u2 = x4[(long)q2.x * 16 + s];
            int4 u3 = x4[(long)q3.x * 16 + s];
            float v0 = __int_as_float(q0.y), v1 = __int_as_float(q1.y);
            float v2 = __int_as_float(q2.y), v3 = __int_as_float(q3.y);
            ACC8(u0, v0);
            ACC8(u1, v1);
            ACC8(u2, v2);
            ACC8(u3, v3);
        }
        for (; j < end; ++j) {
            int2 q = sed[j];
            int4 u = x4[(long)q.x * 16 + s];
            float v = __int_as_float(q.y);
            ACC8(u, v);
        }
        if (row < N) {
            short8 o;
#pragma unroll
            for (int t = 0; t < 8; ++t) o[t] = (short)f2bf(pa[t]);
            *(short8*)(aggb + (long)row * DIM + s * 8) = o;
        }
    }
#undef ACC8
}

// ---- fused MFMA: out = leaky_relu([x+agg@W1^T, x*(agg@W1^T)] @ W2^T) ----
// 64 rows/block, 4 waves; each wave owns 2 output-column tiles for all 64 rows.
// B fragments hoisted into registers once; weight L2 traffic = 1 copy per block.
__global__ __launch_bounds__(256, 4) void k_fused(const unsigned short* __restrict__ aggb,
                                                  const unsigned short* __restrict__ inputb,
                                                  const unsigned short* __restrict__ w1b,
                                                  const unsigned short* __restrict__ w2b,
                                                  float* __restrict__ out, int N) {
    __shared__ __align__(16) unsigned short sh[2 * 64 * 136];   // h0 | h1, rows padded to 136
    int w = threadIdx.x >> 6, lane = threadIdx.x & 63;
    int quad = lane >> 4, lq = lane & 15;
    int blk0 = blockIdx.x * 64;
    unsigned short* sh0 = sh;
    unsigned short* sh1 = sh + 64 * 136;

    // ---- hoisted gemm1 B fragments: nt = 2w, 2w+1 (8 frags = 32 VGPR, issued as a batch)
    short8 b1[2][4];
#pragma unroll
    for (int ntl = 0; ntl < 2; ++ntl)
#pragma unroll
        for (int kb = 0; kb < 4; ++kb)
            b1[ntl][kb] = *(const short8*)(w1b + ((w * 2 + ntl) * 16 + lq) * DIM +
                                           kb * 32 + quad * 8);

    // ---- gemm1 + h write, fused per m-tile to bound VGPR pressure ----
#pragma unroll
    for (int mt = 0; mt < 4; ++mt) {
        short8 afr[4];
        {
            int row = blk0 + mt * 16 + lq; if (row >= N) row = N - 1;
#pragma unroll
            for (int kb = 0; kb < 4; ++kb)
                afr[kb] = *(const short8*)(aggb + (long)row * DIM + kb * 32 + quad * 8);
        }
#pragma unroll
        for (int ntl = 0; ntl < 2; ++ntl) {
            f32x4 c = {0.f, 0.f, 0.f, 0.f};
#pragma unroll
            for (int kb = 0; kb < 4; ++kb)
                c = __builtin_amdgcn_mfma_f32_16x16x32_bf16(afr[kb], b1[ntl][kb], c, 0, 0, 0);
            int nt = w * 2 + ntl;
#pragma unroll
            for (int rg = 0; rg < 4; ++rg) {
                int r = blk0 + mt * 16 + quad * 4 + rg;
                int rr = (r < N) ? r : (N - 1);
                float x = bf2f(inputb[(long)rr * DIM + nt * 16 + lq]);
                float nb = c[rg];
                int off = (mt * 16 + quad * 4 + rg) * 136 + nt * 16 + lq;
                sh0[off] = f2bf(x + nb);
                sh1[off] = f2bf(x * nb);
            }
        }
    }

    // ---- hoisted gemm2 B fragments (16 frags = 64 VGPR), issued BEFORE the barrier ----
    short8 b2[2][8];
#pragma unroll
    for (int ntl = 0; ntl < 2; ++ntl)
#pragma unroll
        for (int kb = 0; kb < 8; ++kb)
            b2[ntl][kb] = *(const short8*)(w2b + ((w * 2 + ntl) * 16 + lq) * 256 +
                                           kb * 32 + quad * 8);
    __syncthreads();

    // ---- gemm2 (K=256 over two h halves) + leaky_relu epilogue, direct store ----
#pragma unroll
    for (int mt = 0; mt < 4; ++mt) {
        int arow = (mt * 16 + lq) * 136;
        short8 a0[4], a1[4];
#pragma unroll
        for (int kb = 0; kb < 4; ++kb) {
            a0[kb] = *(const short8*)(sh0 + arow + kb * 32 + quad * 8);
            a1[kb] = *(const short8*)(sh1 + arow + kb * 32 + quad * 8);
        }
#pragma unroll
        for (int ntl = 0; ntl < 2; ++ntl) {
            f32x4 c = {0.f, 0.f, 0.f, 0.f};
#pragma unroll
            for (int kb = 0; kb < 4; ++kb)
                c = __builtin_amdgcn_mfma_f32_16x16x32_bf16(a0[kb], b2[ntl][kb], c, 0, 0, 0);
#pragma unroll
            for (int kb = 0; kb < 4; ++kb)
                c = __builtin_amdgcn_mfma_f32_16x16x32_bf16(a1[kb], b2[ntl][kb + 4], c, 0, 0, 0);
            int nt = w * 2 + ntl;
#pragma unroll
            for (int rg = 0; rg < 4; ++rg) {
                int r = blk0 + mt * 16 + quad * 4 + rg;
                if (r < N) {
                    float v = c[rg];
                    v = (v > 0.f) ? v : 0.01f * v;
                    out[(long)r * DIM + nt * 16 + lq] = v;
                }
            }
        }
    }
}

extern "C" void kernel_launch(void* const* d_in, const int* in_sizes, int n_in,
                              void* d_out, int out_size, void* d_ws, size_t ws_size,
                              hipStream_t stream) {
    const float* input = (const float*)d_in[0];
    const int*   er    = (const int*)d_in[1];
    const int*   ec    = (const int*)d_in[2];
    const float* ev    = (const float*)d_in[3];
    const float* W1    = (const float*)d_in[4];
    const float* W2    = (const float*)d_in[5];
    int N = in_sizes[0] / DIM;      // 100000
    int E = in_sizes[1];            // 1600000
    float* out = (float*)d_out;
    int nbuk = (N + BROWS - 1) / BROWS;     // 782

    // ---- workspace layout (~71 MB, all chunks 16B-aligned) ----
    int* ws = (int*)d_ws;
    int* gcur = ws;                                                      // nbuk ints (pad 1024)
    int2* edata0 = (int2*)(ws + 1024);                                   // nbuk*BCAP int2
    unsigned short* w1b = (unsigned short*)(edata0 + (long)nbuk * BCAP); // 16384 bf16
    unsigned short* w2b = w1b + 16384;                                   // 32768 bf16
    unsigned short* inputb = w2b + 32768;                                // N*DIM bf16
    unsigned short* aggb = inputb + (long)N * DIM;                       // N*DIM bf16

    int n4 = N * (DIM / 4);
    int nCvt = (n4 + 255) / 256;
    int nZero = (nbuk + 255) / 256;
    k_pre<<<nCvt + 192 + nZero, 256, 0, stream>>>(
        (const float4*)input, W1, W2, inputb, w1b, w2b, gcur, n4, nCvt, nbuk);

    k_bucket<<<(E + BK_EDGES - 1) / BK_EDGES, 1024, 0, stream>>>(
        er, ec, ev, gcur, edata0, E, nbuk);

    k_gather<<<nbuk, 256, 0, stream>>>(inputb, edata0, gcur, aggb, N);

    k_fused<<<(N + 63) / 64, 256, 0, stream>>>(aggb, inputb, w1b, w2b, out, N);
}

// Round 8
// 244.937 us; speedup vs baseline: 1.1304x; 1.0197x over previous
//
#include <hip/hip_runtime.h>

#define DIM 128
#define BROWS 128               // rows per bucket (row >> 7)
#define BCAP 3072               // edata0 capacity per bucket (mean 2046, +22 sigma)
#define HCAP 2048               // per-64-row-half sed capacity (mean 1023, +32 sigma)
#define NBUK_PAD 800
#define BK_EDGES 6144           // edges per k_bucket block (261 blocks), LDS-staged

typedef __attribute__((ext_vector_type(8))) short short8;   // 8 x bf16 (4 VGPR)
typedef __attribute__((ext_vector_type(4))) float f32x4;    // 4 x f32  (4 VGPR)

__device__ __forceinline__ unsigned short f2bf(float f) {   // RNE fp32->bf16
    unsigned u = __float_as_uint(f);
    u += 0x7fffu + ((u >> 16) & 1u);
    return (unsigned short)(u >> 16);
}
__device__ __forceinline__ float bf2f(unsigned short b) {
    return __uint_as_float(((unsigned)b) << 16);
}

// ---- merged pre-pass: input fp32->bf16, W1/W2 fp32->bf16, zero gcur (one launch) ----
__global__ void k_pre(const float4* __restrict__ in, const float* __restrict__ W1,
                      const float* __restrict__ W2, unsigned short* __restrict__ inputb,
                      unsigned short* __restrict__ w1b, unsigned short* __restrict__ w2b,
                      int* __restrict__ gcur, int n4, int nCvt, int nbuk) {
    int b = blockIdx.x;
    if (b < nCvt) {
        int i = b * 256 + threadIdx.x;
        if (i < n4) {
            float4 v = in[i];
            *(ushort4*)(inputb + (long)i * 4) =
                make_ushort4(f2bf(v.x), f2bf(v.y), f2bf(v.z), f2bf(v.w));
        }
    } else if (b < nCvt + 192) {
        int idx = (b - nCvt) * 256 + threadIdx.x;   // 49152 = 16384 + 32768
        if (idx < 16384)      w1b[idx] = f2bf(W1[idx]);
        else                  w2b[idx - 16384] = f2bf(W2[idx - 16384]);
    } else {
        int i = (b - nCvt - 192) * 256 + threadIdx.x;
        if (i < nbuk) gcur[i] = 0;
    }
}

// ---- pass 1: bucket scatter with LDS PRESORT ----
// Each block sorts 6144 edges into 782 row-buckets inside LDS, then writes each
// bucket's run coalesced. Write-out uses 8 lanes/bucket (c~7.9) -> ~100% lane
// efficiency (was 1 wave/bucket = 12%).
__global__ __launch_bounds__(1024) void k_bucket(const int* __restrict__ er,
                                                 const int* __restrict__ ec,
                                                 const float* __restrict__ ev,
                                                 int* __restrict__ gcur,
                                                 int2* __restrict__ edata0, int E, int nbuk) {
    __shared__ int2 sed[BK_EDGES];      // 48 KB sorted edge staging
    __shared__ int lhist[NBUK_PAD];
    __shared__ int lscan[NBUK_PAD];
    __shared__ int lpos[NBUK_PAD];
    __shared__ int gbase[NBUK_PAD];
    int tid = threadIdx.x;
    if (tid < NBUK_PAD) lhist[tid] = 0;
    __syncthreads();
    int e0 = blockIdx.x * BK_EDGES;
    int bcnt = E - e0; if (bcnt > BK_EDGES) bcnt = BK_EDGES;
    for (int i = tid; i < bcnt; i += 1024)
        atomicAdd(&lhist[er[e0 + i] >> 7], 1);
    __syncthreads();
    if (tid < NBUK_PAD) lscan[tid] = lhist[tid];
    __syncthreads();
    for (int off = 1; off < NBUK_PAD; off <<= 1) {          // Hillis-Steele inclusive
        int v = (tid < NBUK_PAD && tid >= off) ? lscan[tid - off] : 0;
        __syncthreads();
        if (tid < NBUK_PAD) lscan[tid] += v;
        __syncthreads();
    }
    if (tid < NBUK_PAD) {
        int c = lhist[tid];
        lpos[tid] = lscan[tid] - c;                         // exclusive: LDS write cursor
        gbase[tid] = (c > 0 && tid < nbuk) ? atomicAdd(&gcur[tid], c) : 0;
    }
    __syncthreads();
    for (int i = tid; i < bcnt; i += 1024) {                // LDS scatter (cheap)
        int e = e0 + i;
        int r = er[e], bk = r >> 7;
        int p = atomicAdd(&lpos[bk], 1);
        sed[p] = make_int2(((r & 127) << 17) | ec[e], __float_as_int(ev[e]));
    }
    __syncthreads();
    int sub = tid & 7, bg = tid >> 3;                       // 128 bucket-groups x 8 lanes
    for (int bk = bg; bk < nbuk; bk += 128) {
        int c = lhist[bk];
        if (c == 0) continue;
        int excl = lscan[bk] - c;
        int gb = gbase[bk];
        long base = (long)bk * BCAP;
        for (int j = sub; j < c; j += 8)
            if (gb + j < BCAP)                              // capacity guard (never)
                edata0[base + gb + j] = sed[excl + j];
    }
}

// ---- gather: one block per 64-row HALF-bucket (grid 2x, LDS 17KB -> ~6 blocks/CU) ----
// Filters its bucket's chunk to its half, builds a 64-row mini-CSR in LDS, then the
// proven 16-lane/row 4-deep-unrolled register gather (edge descriptors from LDS).
__global__ __launch_bounds__(256) void k_gather(const unsigned short* __restrict__ xb,
                                                const int2* __restrict__ edata0,
                                                const int* __restrict__ gcur,
                                                unsigned short* __restrict__ aggb, int N) {
    __shared__ int2 sed[HCAP];          // 16 KB row-sorted (col,val) for this half
    __shared__ int hist[64];
    __shared__ int hscan[64];
    __shared__ int lcur[64];
    int tid = threadIdx.x;
    int bkt = blockIdx.x >> 1, half = blockIdx.x & 1;
    int cnt = gcur[bkt]; if (cnt > BCAP) cnt = BCAP;
    const int2* e0 = edata0 + (long)bkt * BCAP;
    if (tid < 64) hist[tid] = 0;
    __syncthreads();
    for (int i = tid; i < cnt; i += 256) {
        int rl = e0[i].x >> 17;
        if ((rl >> 6) == half) atomicAdd(&hist[rl & 63], 1);
    }
    __syncthreads();
    if (tid < 64) hscan[tid] = hist[tid];
    __syncthreads();
    for (int off = 1; off < 64; off <<= 1) {                // Hillis-Steele inclusive
        int v = (tid < 64 && tid >= off) ? hscan[tid - off] : 0;
        __syncthreads();
        if (tid < 64) hscan[tid] += v;
        __syncthreads();
    }
    if (tid < 64) lcur[tid] = hscan[tid] - hist[tid];
    __syncthreads();
    for (int i = tid; i < cnt; i += 256) {                  // LDS scatter to row order
        int2 v = e0[i];
        int rl = v.x >> 17;
        if ((rl >> 6) == half) {
            int p = atomicAdd(&lcur[rl & 63], 1);
            if (p < HCAP) sed[p] = make_int2(v.x & 0x1FFFF, v.y);
        }
    }
    __syncthreads();

    int slot = tid >> 4, s = tid & 15;      // 16 row-slots, dim-slot s (16B each)
    const int4* x4 = (const int4*)xb;       // 16 x int4 per 256B x-row

#define ACC8(U, V)                                                         \
    {                                                                      \
        const unsigned* wp_ = (const unsigned*)&(U);                       \
        pa[0] += (V) * __uint_as_float(wp_[0] << 16);                      \
        pa[1] += (V) * __uint_as_float(wp_[0] & 0xffff0000u);              \
        pa[2] += (V) * __uint_as_float(wp_[1] << 16);                      \
        pa[3] += (V) * __uint_as_float(wp_[1] & 0xffff0000u);              \
        pa[4] += (V) * __uint_as_float(wp_[2] << 16);                      \
        pa[5] += (V) * __uint_as_float(wp_[2] & 0xffff0000u);              \
        pa[6] += (V) * __uint_as_float(wp_[3] << 16);                      \
        pa[7] += (V) * __uint_as_float(wp_[3] & 0xffff0000u);              \
    }

    for (int k = 0; k < 4; ++k) {           // 4 rows per slot
        int rl = k * 16 + slot;
        int row = bkt * BROWS + (half << 6) + rl;
        int beg = hscan[rl] - hist[rl], end = hscan[rl];
        if (beg > HCAP) beg = HCAP;
        if (end > HCAP) end = HCAP;
        float pa[8];
#pragma unroll
        for (int t = 0; t < 8; ++t) pa[t] = 0.f;
        int j = beg;
        for (; j + 4 <= end; j += 4) {      // 4 independent 16B x-loads in flight
            int2 q0 = sed[j], q1 = sed[j + 1], q2 = sed[j + 2], q3 = sed[j + 3];
            int4 u0 = x4[(long)q0.x * 16 + s];
            int4 u1 = x4[(long)q1.x * 16 + s];
            int4 u2 = x4[(long)q2.x * 16 + s];
            int4 u3 = x4[(long)q3.x * 16 + s];
            float v0 = __int_as_float(q0.y), v1 = __int_as_float(q1.y);
            float v2 = __int_as_float(q2.y), v3 = __int_as_float(q3.y);
            ACC8(u0, v0);
            ACC8(u1, v1);
            ACC8(u2, v2);
            ACC8(u3, v3);
        }
        for (; j < end; ++j) {
            int2 q = sed[j];
            int4 u = x4[(long)q.x * 16 + s];
            float v = __int_as_float(q.y);
            ACC8(u, v);
        }
        if (row < N) {
            short8 o;
#pragma unroll
            for (int t = 0; t < 8; ++t) o[t] = (short)f2bf(pa[t]);
            *(short8*)(aggb + (long)row * DIM + s * 8) = o;
        }
    }
#undef ACC8
}

// ---- fused MFMA: out = leaky_relu([x+agg@W1^T, x*(agg@W1^T)] @ W2^T) ----
// 64 rows/block, 4 waves; each wave owns 2 output-column tiles for all 64 rows.
// NEW: x-tile staged in LDS (coalesced short8) -> h-phase reads LDS instead of
// 32 scalar GLOBAL ushort loads/thread at L2 latency (prime suspect for the 44us).
// Row stride 136 keeps the scalar LDS reads ~2-way bank-aliased (free).
__global__ __launch_bounds__(256, 3) void k_fused(const unsigned short* __restrict__ aggb,
                                                  const unsigned short* __restrict__ inputb,
                                                  const unsigned short* __restrict__ w1b,
                                                  const unsigned short* __restrict__ w2b,
                                                  float* __restrict__ out, int N) {
    __shared__ __align__(16) unsigned short sh[2 * 64 * 136];   // h0 | h1 (34.8 KB)
    __shared__ __align__(16) unsigned short xs[64 * 136];       // x tile  (17.4 KB)
    int w = threadIdx.x >> 6, lane = threadIdx.x & 63;
    int quad = lane >> 4, lq = lane & 15;
    int blk0 = blockIdx.x * 64;
    unsigned short* sh0 = sh;
    unsigned short* sh1 = sh + 64 * 136;

    // ---- stage x tile: 64 rows x 128 dims, coalesced short8 loads ----
    for (int i = threadIdx.x; i < 64 * 16; i += 256) {
        int row = i >> 4, c = i & 15;
        int rr = blk0 + row; if (rr >= N) rr = N - 1;
        *(short8*)(xs + row * 136 + c * 8) =
            *(const short8*)(inputb + (long)rr * DIM + c * 8);
    }

    // ---- hoisted gemm1 B fragments: nt = 2w, 2w+1 (8 frags = 32 VGPR) ----
    short8 b1[2][4];
#pragma unroll
    for (int ntl = 0; ntl < 2; ++ntl)
#pragma unroll
        for (int kb = 0; kb < 4; ++kb)
            b1[ntl][kb] = *(const short8*)(w1b + ((w * 2 + ntl) * 16 + lq) * DIM +
                                           kb * 32 + quad * 8);
    __syncthreads();                    // xs ready before h-phase reads

    // ---- gemm1 + h write, fused per m-tile to bound VGPR pressure ----
#pragma unroll
    for (int mt = 0; mt < 4; ++mt) {
        short8 afr[4];
        {
            int row = blk0 + mt * 16 + lq; if (row >= N) row = N - 1;
#pragma unroll
            for (int kb = 0; kb < 4; ++kb)
                afr[kb] = *(const short8*)(aggb + (long)row * DIM + kb * 32 + quad * 8);
        }
#pragma unroll
        for (int ntl = 0; ntl < 2; ++ntl) {
            f32x4 c = {0.f, 0.f, 0.f, 0.f};
#pragma unroll
            for (int kb = 0; kb < 4; ++kb)
                c = __builtin_amdgcn_mfma_f32_16x16x32_bf16(afr[kb], b1[ntl][kb], c, 0, 0, 0);
            int nt = w * 2 + ntl;
#pragma unroll
            for (int rg = 0; rg < 4; ++rg) {
                int lrow = mt * 16 + quad * 4 + rg;
                float x = bf2f(xs[lrow * 136 + nt * 16 + lq]);
                float nb = c[rg];
                int off = lrow * 136 + nt * 16 + lq;
                sh0[off] = f2bf(x + nb);
                sh1[off] = f2bf(x * nb);
            }
        }
    }

    // ---- hoisted gemm2 B fragments (16 frags = 64 VGPR), issued BEFORE the barrier ----
    short8 b2[2][8];
#pragma unroll
    for (int ntl = 0; ntl < 2; ++ntl)
#pragma unroll
        for (int kb = 0; kb < 8; ++kb)
            b2[ntl][kb] = *(const short8*)(w2b + ((w * 2 + ntl) * 16 + lq) * 256 +
                                           kb * 32 + quad * 8);
    __syncthreads();

    // ---- gemm2 (K=256 over two h halves) + leaky_relu epilogue, direct store ----
#pragma unroll
    for (int mt = 0; mt < 4; ++mt) {
        int arow = (mt * 16 + lq) * 136;
        short8 a0[4], a1[4];
#pragma unroll
        for (int kb = 0; kb < 4; ++kb) {
            a0[kb] = *(const short8*)(sh0 + arow + kb * 32 + quad * 8);
            a1[kb] = *(const short8*)(sh1 + arow + kb * 32 + quad * 8);
        }
#pragma unroll
        for (int ntl = 0; ntl < 2; ++ntl) {
            f32x4 c = {0.f, 0.f, 0.f, 0.f};
#pragma unroll
            for (int kb = 0; kb < 4; ++kb)
                c = __builtin_amdgcn_mfma_f32_16x16x32_bf16(a0[kb], b2[ntl][kb], c, 0, 0, 0);
#pragma unroll
            for (int kb = 0; kb < 4; ++kb)
                c = __builtin_amdgcn_mfma_f32_16x16x32_bf16(a1[kb], b2[ntl][kb + 4], c, 0, 0, 0);
            int nt = w * 2 + ntl;
#pragma unroll
            for (int rg = 0; rg < 4; ++rg) {
                int r = blk0 + mt * 16 + quad * 4 + rg;
                if (r < N) {
                    float v = c[rg];
                    v = (v > 0.f) ? v : 0.01f * v;
                    out[(long)r * DIM + nt * 16 + lq] = v;
                }
            }
        }
    }
}

extern "C" void kernel_launch(void* const* d_in, const int* in_sizes, int n_in,
                              void* d_out, int out_size, void* d_ws, size_t ws_size,
                              hipStream_t stream) {
    const float* input = (const float*)d_in[0];
    const int*   er    = (const int*)d_in[1];
    const int*   ec    = (const int*)d_in[2];
    const float* ev    = (const float*)d_in[3];
    const float* W1    = (const float*)d_in[4];
    const float* W2    = (const float*)d_in[5];
    int N = in_sizes[0] / DIM;      // 100000
    int E = in_sizes[1];            // 1600000
    float* out = (float*)d_out;
    int nbuk = (N + BROWS - 1) / BROWS;     // 782

    // ---- workspace layout (~71 MB, all chunks 16B-aligned) ----
    int* ws = (int*)d_ws;
    int* gcur = ws;                                                      // nbuk ints (pad 1024)
    int2* edata0 = (int2*)(ws + 1024);                                   // nbuk*BCAP int2
    unsigned short* w1b = (unsigned short*)(edata0 + (long)nbuk * BCAP); // 16384 bf16
    unsigned short* w2b = w1b + 16384;                                   // 32768 bf16
    unsigned short* inputb = w2b + 32768;                                // N*DIM bf16
    unsigned short* aggb = inputb + (long)N * DIM;                       // N*DIM bf16

    int n4 = N * (DIM / 4);
    int nCvt = (n4 + 255) / 256;
    int nZero = (nbuk + 255) / 256;
    k_pre<<<nCvt + 192 + nZero, 256, 0, stream>>>(
        (const float4*)input, W1, W2, inputb, w1b, w2b, gcur, n4, nCvt, nbuk);

    k_bucket<<<(E + BK_EDGES - 1) / BK_EDGES, 1024, 0, stream>>>(
        er, ec, ev, gcur, edata0, E, nbuk);

    k_gather<<<nbuk * 2, 256, 0, stream>>>(inputb, edata0, gcur, aggb, N);

    k_fused<<<(N + 63) / 64, 256, 0, stream>>>(aggb, inputb, w1b, w2b, out, N);
}

// Round 9
// 233.912 us; speedup vs baseline: 1.1837x; 1.0471x over previous
//
#include <hip/hip_runtime.h>

#define DIM 128
#define BROWS 128               // rows per bucket (row >> 7)
#define BCAP 3072               // edata0 capacity per bucket (mean 2046, +22 sigma)
#define NBUK_PAD 800
#define BK_EDGES 6144           // edges per bucket-section block (261 blocks)

typedef __attribute__((ext_vector_type(8))) short short8;   // 8 x bf16 (4 VGPR)
typedef __attribute__((ext_vector_type(4))) float f32x4;    // 4 x f32  (4 VGPR)

__device__ __forceinline__ unsigned short f2bf(float f) {   // RNE fp32->bf16
    unsigned u = __float_as_uint(f);
    u += 0x7fffu + ((u >> 16) & 1u);
    return (unsigned short)(u >> 16);
}
__device__ __forceinline__ float bf2f(unsigned short b) {
    return __uint_as_float(((unsigned)b) << 16);
}

// ---- tiny pre-launch: zero gcur (ordering safety for the merged k_prep) ----
__global__ void k_zero(int* __restrict__ gcur, int nbuk) {
    int i = threadIdx.x;
    if (i < nbuk) gcur[i] = 0;
}

// ---- MERGED prep: bucket-scatter blocks FIRST (latency-heavy, few blocks),
//      then weight convert, then input convert (3125 streaming blocks that
//      overlap-hide the bucket section). Disjoint data -> merge-safe.
__global__ __launch_bounds__(1024) void k_prep(const float4* __restrict__ in,
                                               const float* __restrict__ W1,
                                               const float* __restrict__ W2,
                                               const int* __restrict__ er,
                                               const int* __restrict__ ec,
                                               const float* __restrict__ ev,
                                               int* __restrict__ gcur,
                                               int2* __restrict__ edata0,
                                               unsigned short* __restrict__ inputb,
                                               unsigned short* __restrict__ w1b,
                                               unsigned short* __restrict__ w2b,
                                               int E, int nbuk, int nBkt, int n4) {
    __shared__ int2 sed[BK_EDGES];      // 48 KB sorted edge staging
    __shared__ int lhist[NBUK_PAD];
    __shared__ int lscan[NBUK_PAD];
    __shared__ int lpos[NBUK_PAD];
    __shared__ int gbase[NBUK_PAD];
    int b = blockIdx.x, tid = threadIdx.x;

    if (b < nBkt) {
        // ---- bucket scatter with LDS presort (coalesced run write-out) ----
        if (tid < NBUK_PAD) lhist[tid] = 0;
        __syncthreads();
        int e0 = b * BK_EDGES;
        int bcnt = E - e0; if (bcnt > BK_EDGES) bcnt = BK_EDGES;
        for (int i = tid; i < bcnt; i += 1024)
            atomicAdd(&lhist[er[e0 + i] >> 7], 1);
        __syncthreads();
        if (tid < NBUK_PAD) lscan[tid] = lhist[tid];
        __syncthreads();
        for (int off = 1; off < NBUK_PAD; off <<= 1) {      // Hillis-Steele inclusive
            int v = (tid < NBUK_PAD && tid >= off) ? lscan[tid - off] : 0;
            __syncthreads();
            if (tid < NBUK_PAD) lscan[tid] += v;
            __syncthreads();
        }
        if (tid < NBUK_PAD) {
            int c = lhist[tid];
            lpos[tid] = lscan[tid] - c;                     // exclusive: LDS write cursor
            gbase[tid] = (c > 0 && tid < nbuk) ? atomicAdd(&gcur[tid], c) : 0;
        }
        __syncthreads();
        for (int i = tid; i < bcnt; i += 1024) {            // LDS scatter (cheap)
            int e = e0 + i;
            int r = er[e], bk = r >> 7;
            int p = atomicAdd(&lpos[bk], 1);
            sed[p] = make_int2(((r & 127) << 17) | ec[e], __float_as_int(ev[e]));
        }
        __syncthreads();
        int sub = tid & 7, bg = tid >> 3;                   // 128 bucket-groups x 8 lanes
        for (int bk = bg; bk < nbuk; bk += 128) {
            int c = lhist[bk];
            if (c == 0) continue;
            int excl = lscan[bk] - c;
            int gb = gbase[bk];
            long base = (long)bk * BCAP;
            for (int j = sub; j < c; j += 8)
                if (gb + j < BCAP)                          // capacity guard (never)
                    edata0[base + gb + j] = sed[excl + j];
        }
    } else if (b < nBkt + 48) {
        // ---- weights fp32->bf16 (49152 = 48 x 1024) ----
        int idx = (b - nBkt) * 1024 + tid;
        if (idx < 16384)      w1b[idx] = f2bf(W1[idx]);
        else                  w2b[idx - 16384] = f2bf(W2[idx - 16384]);
    } else {
        // ---- input fp32->bf16, float4 vectorized ----
        int i = (b - nBkt - 48) * 1024 + tid;
        if (i < n4) {
            float4 v = in[i];
            *(ushort4*)(inputb + (long)i * 4) =
                make_ushort4(f2bf(v.x), f2bf(v.y), f2bf(v.z), f2bf(v.w));
        }
    }
}

// ---- gather: ONE block per 128-row bucket, 512 threads (8 waves) ----
// Single-pass in-LDS CSR build (R7) + 32 row-slots x 4 rows gather (R8's occupancy
// without its duplicated sort work). LDS 25.5 KB -> 3 blocks/CU, ~24 waves/CU.
__global__ __launch_bounds__(512) void k_gather(const unsigned short* __restrict__ xb,
                                                const int2* __restrict__ edata0,
                                                const int* __restrict__ gcur,
                                                unsigned short* __restrict__ aggb, int N) {
    __shared__ int2 sed[BCAP];          // 24.6 KB row-sorted (col,val)
    __shared__ int hist[BROWS];
    __shared__ int hscan[BROWS];
    __shared__ int lcur[BROWS];
    int tid = threadIdx.x, b = blockIdx.x;
    int cnt = gcur[b]; if (cnt > BCAP) cnt = BCAP;
    const int2* e0 = edata0 + (long)b * BCAP;
    if (tid < BROWS) hist[tid] = 0;
    __syncthreads();
    for (int i = tid; i < cnt; i += 512) atomicAdd(&hist[e0[i].x >> 17], 1);
    __syncthreads();
    if (tid < BROWS) hscan[tid] = hist[tid];
    __syncthreads();
    for (int off = 1; off < BROWS; off <<= 1) {             // Hillis-Steele inclusive
        int v = (tid < BROWS && tid >= off) ? hscan[tid - off] : 0;
        __syncthreads();
        if (tid < BROWS) hscan[tid] += v;
        __syncthreads();
    }
    if (tid < BROWS) lcur[tid] = hscan[tid] - hist[tid];
    __syncthreads();
    for (int i = tid; i < cnt; i += 512) {                  // LDS scatter to row order
        int2 v = e0[i];
        int p = atomicAdd(&lcur[v.x >> 17], 1);
        sed[p] = make_int2(v.x & 0x1FFFF, v.y);
    }
    __syncthreads();

    int slot = tid >> 4, s = tid & 15;      // 32 row-slots, dim-slot s (16B each)
    const int4* x4 = (const int4*)xb;       // 16 x int4 per 256B x-row

#define ACC8(U, V)                                                         \
    {                                                                      \
        const unsigned* wp_ = (const unsigned*)&(U);                       \
        pa[0] += (V) * __uint_as_float(wp_[0] << 16);                      \
        pa[1] += (V) * __uint_as_float(wp_[0] & 0xffff0000u);              \
        pa[2] += (V) * __uint_as_float(wp_[1] << 16);                      \
        pa[3] += (V) * __uint_as_float(wp_[1] & 0xffff0000u);              \
        pa[4] += (V) * __uint_as_float(wp_[2] << 16);                      \
        pa[5] += (V) * __uint_as_float(wp_[2] & 0xffff0000u);              \
        pa[6] += (V) * __uint_as_float(wp_[3] << 16);                      \
        pa[7] += (V) * __uint_as_float(wp_[3] & 0xffff0000u);              \
    }

    for (int k = 0; k < 4; ++k) {           // 4 rows per slot
        int rl = k * 32 + slot;
        int row = b * BROWS + rl;
        int beg = hscan[rl] - hist[rl], end = hscan[rl];
        float pa[8];
#pragma unroll
        for (int t = 0; t < 8; ++t) pa[t] = 0.f;
        int j = beg;
        for (; j + 4 <= end; j += 4) {      // 4 independent 16B x-loads in flight
            int2 q0 = sed[j], q1 = sed[j + 1], q2 = sed[j + 2], q3 = sed[j + 3];
            int4 u0 = x4[(long)q0.x * 16 + s];
            int4 u1 = x4[(long)q1.x * 16 + s];
            int4 u2 = x4[(long)q2.x * 16 + s];
            int4 u3 = x4[(long)q3.x * 16 + s];
            float v0 = __int_as_float(q0.y), v1 = __int_as_float(q1.y);
            float v2 = __int_as_float(q2.y), v3 = __int_as_float(q3.y);
            ACC8(u0, v0);
            ACC8(u1, v1);
            ACC8(u2, v2);
            ACC8(u3, v3);
        }
        for (; j < end; ++j) {
            int2 q = sed[j];
            int4 u = x4[(long)q.x * 16 + s];
            float v = __int_as_float(q.y);
            ACC8(u, v);
        }
        if (row < N) {
            short8 o;
#pragma unroll
            for (int t = 0; t < 8; ++t) o[t] = (short)f2bf(pa[t]);
            *(short8*)(aggb + (long)row * DIM + s * 8) = o;
        }
    }
#undef ACC8
}

// ---- fused MFMA: out = leaky_relu([x+agg@W1^T, x*(agg@W1^T)] @ W2^T) ----
// 64 rows/block, 4 waves; each wave owns 2 output-column tiles for all 64 rows.
// x-tile staged in LDS (coalesced short8); h-phase reads LDS, not scalar global.
__global__ __launch_bounds__(256, 3) void k_fused(const unsigned short* __restrict__ aggb,
                                                  const unsigned short* __restrict__ inputb,
                                                  const unsigned short* __restrict__ w1b,
                                                  const unsigned short* __restrict__ w2b,
                                                  float* __restrict__ out, int N) {
    __shared__ __align__(16) unsigned short sh[2 * 64 * 136];   // h0 | h1 (34.8 KB)
    __shared__ __align__(16) unsigned short xs[64 * 136];       // x tile  (17.4 KB)
    int w = threadIdx.x >> 6, lane = threadIdx.x & 63;
    int quad = lane >> 4, lq = lane & 15;
    int blk0 = blockIdx.x * 64;
    unsigned short* sh0 = sh;
    unsigned short* sh1 = sh + 64 * 136;

    // ---- stage x tile: 64 rows x 128 dims, coalesced short8 loads ----
    for (int i = threadIdx.x; i < 64 * 16; i += 256) {
        int row = i >> 4, c = i & 15;
        int rr = blk0 + row; if (rr >= N) rr = N - 1;
        *(short8*)(xs + row * 136 + c * 8) =
            *(const short8*)(inputb + (long)rr * DIM + c * 8);
    }

    // ---- hoisted gemm1 B fragments: nt = 2w, 2w+1 (8 frags = 32 VGPR) ----
    short8 b1[2][4];
#pragma unroll
    for (int ntl = 0; ntl < 2; ++ntl)
#pragma unroll
        for (int kb = 0; kb < 4; ++kb)
            b1[ntl][kb] = *(const short8*)(w1b + ((w * 2 + ntl) * 16 + lq) * DIM +
                                           kb * 32 + quad * 8);
    __syncthreads();                    // xs ready before h-phase reads

    // ---- gemm1 + h write, fused per m-tile to bound VGPR pressure ----
#pragma unroll
    for (int mt = 0; mt < 4; ++mt) {
        short8 afr[4];
        {
            int row = blk0 + mt * 16 + lq; if (row >= N) row = N - 1;
#pragma unroll
            for (int kb = 0; kb < 4; ++kb)
                afr[kb] = *(const short8*)(aggb + (long)row * DIM + kb * 32 + quad * 8);
        }
#pragma unroll
        for (int ntl = 0; ntl < 2; ++ntl) {
            f32x4 c = {0.f, 0.f, 0.f, 0.f};
#pragma unroll
            for (int kb = 0; kb < 4; ++kb)
                c = __builtin_amdgcn_mfma_f32_16x16x32_bf16(afr[kb], b1[ntl][kb], c, 0, 0, 0);
            int nt = w * 2 + ntl;
#pragma unroll
            for (int rg = 0; rg < 4; ++rg) {
                int lrow = mt * 16 + quad * 4 + rg;
                float x = bf2f(xs[lrow * 136 + nt * 16 + lq]);
                float nb = c[rg];
                int off = lrow * 136 + nt * 16 + lq;
                sh0[off] = f2bf(x + nb);
                sh1[off] = f2bf(x * nb);
            }
        }
    }

    // ---- hoisted gemm2 B fragments (16 frags = 64 VGPR), issued BEFORE the barrier ----
    short8 b2[2][8];
#pragma unroll
    for (int ntl = 0; ntl < 2; ++ntl)
#pragma unroll
        for (int kb = 0; kb < 8; ++kb)
            b2[ntl][kb] = *(const short8*)(w2b + ((w * 2 + ntl) * 16 + lq) * 256 +
                                           kb * 32 + quad * 8);
    __syncthreads();

    // ---- gemm2 (K=256 over two h halves) + leaky_relu epilogue, direct store ----
#pragma unroll
    for (int mt = 0; mt < 4; ++mt) {
        int arow = (mt * 16 + lq) * 136;
        short8 a0[4], a1[4];
#pragma unroll
        for (int kb = 0; kb < 4; ++kb) {
            a0[kb] = *(const short8*)(sh0 + arow + kb * 32 + quad * 8);
            a1[kb] = *(const short8*)(sh1 + arow + kb * 32 + quad * 8);
        }
#pragma unroll
        for (int ntl = 0; ntl < 2; ++ntl) {
            f32x4 c = {0.f, 0.f, 0.f, 0.f};
#pragma unroll
            for (int kb = 0; kb < 4; ++kb)
                c = __builtin_amdgcn_mfma_f32_16x16x32_bf16(a0[kb], b2[ntl][kb], c, 0, 0, 0);
#pragma unroll
            for (int kb = 0; kb < 4; ++kb)
                c = __builtin_amdgcn_mfma_f32_16x16x32_bf16(a1[kb], b2[ntl][kb + 4], c, 0, 0, 0);
            int nt = w * 2 + ntl;
#pragma unroll
            for (int rg = 0; rg < 4; ++rg) {
                int r = blk0 + mt * 16 + quad * 4 + rg;
                if (r < N) {
                    float v = c[rg];
                    v = (v > 0.f) ? v : 0.01f * v;
                    out[(long)r * DIM + nt * 16 + lq] = v;
                }
            }
        }
    }
}

extern "C" void kernel_launch(void* const* d_in, const int* in_sizes, int n_in,
                              void* d_out, int out_size, void* d_ws, size_t ws_size,
                              hipStream_t stream) {
    const float* input = (const float*)d_in[0];
    const int*   er    = (const int*)d_in[1];
    const int*   ec    = (const int*)d_in[2];
    const float* ev    = (const float*)d_in[3];
    const float* W1    = (const float*)d_in[4];
    const float* W2    = (const float*)d_in[5];
    int N = in_sizes[0] / DIM;      // 100000
    int E = in_sizes[1];            // 1600000
    float* out = (float*)d_out;
    int nbuk = (N + BROWS - 1) / BROWS;     // 782

    // ---- workspace layout (~71 MB, all chunks 16B-aligned) ----
    int* ws = (int*)d_ws;
    int* gcur = ws;                                                      // nbuk ints (pad 1024)
    int2* edata0 = (int2*)(ws + 1024);                                   // nbuk*BCAP int2
    unsigned short* w1b = (unsigned short*)(edata0 + (long)nbuk * BCAP); // 16384 bf16
    unsigned short* w2b = w1b + 16384;                                   // 32768 bf16
    unsigned short* inputb = w2b + 32768;                                // N*DIM bf16
    unsigned short* aggb = inputb + (long)N * DIM;                       // N*DIM bf16

    int n4 = N * (DIM / 4);                 // 3.2M float4 groups
    int nBkt = (E + BK_EDGES - 1) / BK_EDGES;           // 261
    int nCvt = (n4 + 1023) / 1024;                      // 3125

    k_zero<<<1, 1024, 0, stream>>>(gcur, nbuk);

    k_prep<<<nBkt + 48 + nCvt, 1024, 0, stream>>>(
        (const float4*)input, W1, W2, er, ec, ev, gcur, edata0,
        inputb, w1b, w2b, E, nbuk, nBkt, n4);

    k_gather<<<nbuk, 512, 0, stream>>>(inputb, edata0, gcur, aggb, N);

    k_fused<<<(N + 63) / 64, 256, 0, stream>>>(aggb, inputb, w1b, w2b, out, N);
}